// Round 1
// baseline (287.219 us; speedup 1.0000x reference)
//
#include <hip/hip_runtime.h>
#include <math.h>

// Problem constants: B=64, N=4096, K=128. Labels C in [0,128).
// out[b,i,k] = (rank(C[b,i]) == k) ? u : ndtri(clip(U,1e-7,1-1e-7) * Phi(u))
// where u = mu + sigma*eps[b,i], rank = index into sorted unique values of C.

// --- Pass 1: presence bitmap over C (handles jnp.unique relabeling exactly) ---
__global__ void presence_kernel(const int* __restrict__ C, int n,
                                unsigned* __restrict__ mask) {
    unsigned m0 = 0, m1 = 0, m2 = 0, m3 = 0;
    int stride = gridDim.x * blockDim.x;
    for (int i = blockIdx.x * blockDim.x + threadIdx.x; i < n; i += stride) {
        int c = C[i];
        unsigned bit = 1u << (c & 31);
        int w = (c >> 5) & 3;
        m0 |= (w == 0) ? bit : 0u;
        m1 |= (w == 1) ? bit : 0u;
        m2 |= (w == 2) ? bit : 0u;
        m3 |= (w == 3) ? bit : 0u;
    }
    // wave-64 OR reduction
    #pragma unroll
    for (int off = 32; off > 0; off >>= 1) {
        m0 |= __shfl_down(m0, off, 64);
        m1 |= __shfl_down(m1, off, 64);
        m2 |= __shfl_down(m2, off, 64);
        m3 |= __shfl_down(m3, off, 64);
    }
    if ((threadIdx.x & 63) == 0) {
        if (m0) atomicOr(&mask[0], m0);
        if (m1) atomicOr(&mask[1], m1);
        if (m2) atomicOr(&mask[2], m2);
        if (m3) atomicOr(&mask[3], m3);
    }
}

// --- Pass 2: main elementwise kernel, one thread per float4 (4 k-values) ---
__global__ void __launch_bounds__(256) map_kernel(
    const int* __restrict__ C,
    const float* __restrict__ eps,
    const float4* __restrict__ U4,
    const float* __restrict__ mu_p,
    const float* __restrict__ sigma_p,
    const unsigned* __restrict__ mask,
    float4* __restrict__ out4,
    int total4)
{
    int idx = blockIdx.x * blockDim.x + threadIdx.x;
    if (idx >= total4) return;
    int row = idx >> 5;        // K/4 = 32 float4 per (b,i) row
    int k0  = (idx & 31) << 2; // starting k of this thread's 4 elements

    float mu = mu_p[0];
    float sigma = sigma_p[0];
    float u = fmaf(sigma, eps[row], mu);
    // Phi(u) = 0.5*erfc(-u/sqrt(2))
    float phi = 0.5f * erfcf(-u * 0.7071067811865476f);

    // rank of c among present values = popcount of presence bits strictly below c
    int c = C[row];
    unsigned w0 = mask[0], w1 = mask[1], w2 = mask[2], w3 = mask[3];
    int cw = c >> 5;
    unsigned below = (1u << (c & 31)) - 1u;
    int rank = __popc(w0 & ((0 < cw) ? 0xFFFFFFFFu : ((0 == cw) ? below : 0u)))
             + __popc(w1 & ((1 < cw) ? 0xFFFFFFFFu : ((1 == cw) ? below : 0u)))
             + __popc(w2 & ((2 < cw) ? 0xFFFFFFFFu : ((2 == cw) ? below : 0u)))
             + __popc(w3 & ((3 < cw) ? 0xFFFFFFFFu : ((3 == cw) ? below : 0u)));

    float4 Uv = U4[idx];
    const float lo = 1e-7f;
    const float hi = 0.99999988079071045f; // fp32(1.0 - 1e-7), matches jnp.clip
    float us0 = Uv.x, us1 = Uv.y, us2 = Uv.z, us3 = Uv.w;

    // ndtri(p) = -sqrt(2) * erfcinv(2p)
    float p;
    p = fminf(fmaxf(us0, lo), hi) * phi;
    float z0 = -1.4142135623730951f * erfcinvf(2.0f * p);
    p = fminf(fmaxf(us1, lo), hi) * phi;
    float z1 = -1.4142135623730951f * erfcinvf(2.0f * p);
    p = fminf(fmaxf(us2, lo), hi) * phi;
    float z2 = -1.4142135623730951f * erfcinvf(2.0f * p);
    p = fminf(fmaxf(us3, lo), hi) * phi;
    float z3 = -1.4142135623730951f * erfcinvf(2.0f * p);

    float4 o;
    o.x = (k0 + 0 == rank) ? u : z0;
    o.y = (k0 + 1 == rank) ? u : z1;
    o.z = (k0 + 2 == rank) ? u : z2;
    o.w = (k0 + 3 == rank) ? u : z3;
    out4[idx] = o;
}

extern "C" void kernel_launch(void* const* d_in, const int* in_sizes, int n_in,
                              void* d_out, int out_size, void* d_ws, size_t ws_size,
                              hipStream_t stream) {
    const int*   C     = (const int*)d_in[0];
    const float* eps   = (const float*)d_in[1];
    const float4* U4   = (const float4*)d_in[2];
    const float* mu    = (const float*)d_in[3];
    const float* sigma = (const float*)d_in[4];
    float4* out4 = (float4*)d_out;
    unsigned* mask = (unsigned*)d_ws;

    int n = in_sizes[0];           // B*N = 262144
    int total4 = out_size / 4;     // B*N*K/4 = 8388608

    // d_ws is re-poisoned to 0xAA before every launch — zero the 16-byte mask.
    hipMemsetAsync(d_ws, 0, 4 * sizeof(unsigned), stream);
    presence_kernel<<<256, 256, 0, stream>>>(C, n, mask);

    int blocks = (total4 + 255) / 256;
    map_kernel<<<blocks, 256, 0, stream>>>(C, eps, U4, mu, sigma, mask, out4, total4);
}

// Round 2
// 243.613 us; speedup vs baseline: 1.1790x; 1.1790x over previous
//
#include <hip/hip_runtime.h>
#include <math.h>

// Problem: B=64, N=4096, K=128. Labels C in [0,128).
// out[b,i,k] = (rank(C[b,i]) == k) ? u : ndtri(clip(U,1e-7,1-1e-7) * Phi(u))
// where u = mu + sigma*eps[b,i], rank = index of C[b,i] in sorted unique(C).
//
// Structure:
//   ws[0..3]   : 128-bit presence bitmap over label values (zeroed via memset)
//   ws+256    : float2 {u, Phi(u)} per row (2 MB)
// Pass 1 (row_kernel): presence bitmap + per-row u/phi  (262144 threads)
// Pass 2 (map_kernel): one thread per float4 of U; custom fp32 Acklam ndtri.

// ---------------------------------------------------------------------------
// Acklam's inverse normal CDF, fp32. |rel err| ~1e-4 worst-case in fp32 eval,
// valid for p in [1e-30, 1-1.2e-7]. Our p range: [~3e-13, 0.99999988].
__device__ __forceinline__ float ndtri_acklam(float p) {
    const float omp = 1.0f - p;
    const bool upper = p > 0.5f;
    const float pm = upper ? omp : p;   // min(p, 1-p)
    float x;
    if (pm < 0.02425f) {
        // tail: q = sqrt(-2 ln pm)
        float q = sqrtf(-2.0f * __logf(pm));
        float num = -0.007784894002430293f;
        num = fmaf(num, q, -0.3223964580411365f);
        num = fmaf(num, q, -2.400758277161838f);
        num = fmaf(num, q, -2.549732539343734f);
        num = fmaf(num, q,  4.374664141464968f);
        num = fmaf(num, q,  2.938163982698783f);
        float den = 0.007784695709041462f;
        den = fmaf(den, q, 0.3224671290700398f);
        den = fmaf(den, q, 2.445134137142996f);
        den = fmaf(den, q, 3.754408661907416f);
        den = fmaf(den, q, 1.0f);
        x = num * __builtin_amdgcn_rcpf(den);   // negative (lower-tail value)
        if (upper) x = -x;
    } else {
        // central: rational in r = (p-0.5)^2
        float q = p - 0.5f;
        float r = q * q;
        float num = -39.69683028665376f;
        num = fmaf(num, r,  220.9460984245205f);
        num = fmaf(num, r, -275.9285104469687f);
        num = fmaf(num, r,  138.3577518672690f);
        num = fmaf(num, r,  -30.66479806614716f);
        num = fmaf(num, r,    2.506628277459239f);
        float den = -54.47609879822406f;
        den = fmaf(den, r,  161.5858368580409f);
        den = fmaf(den, r, -155.6989798598866f);
        den = fmaf(den, r,   66.80131188771972f);
        den = fmaf(den, r,  -13.28068155288572f);
        den = fmaf(den, r,    1.0f);
        x = q * num * __builtin_amdgcn_rcpf(den);
    }
    return x;
}

// ---------------------------------------------------------------------------
// Pass 1: presence bitmap + per-row (u, Phi(u))
__global__ void __launch_bounds__(256) row_kernel(
    const int* __restrict__ C,
    const float* __restrict__ eps,
    const float* __restrict__ mu_p,
    const float* __restrict__ sigma_p,
    unsigned* __restrict__ mask,
    float2* __restrict__ uphi,
    int n)
{
    __shared__ unsigned sm[4];
    if (threadIdx.x < 4) sm[threadIdx.x] = 0u;
    __syncthreads();

    int i = blockIdx.x * blockDim.x + threadIdx.x;
    unsigned m0 = 0, m1 = 0, m2 = 0, m3 = 0;
    if (i < n) {
        int c = C[i];
        float u = fmaf(sigma_p[0], eps[i], mu_p[0]);
        float phi = 0.5f * erfcf(-u * 0.7071067811865476f);
        uphi[i] = make_float2(u, phi);
        unsigned bit = 1u << (c & 31);
        int w = (c >> 5) & 3;
        m0 = (w == 0) ? bit : 0u;
        m1 = (w == 1) ? bit : 0u;
        m2 = (w == 2) ? bit : 0u;
        m3 = (w == 3) ? bit : 0u;
    }
    #pragma unroll
    for (int off = 32; off > 0; off >>= 1) {
        m0 |= __shfl_down(m0, off, 64);
        m1 |= __shfl_down(m1, off, 64);
        m2 |= __shfl_down(m2, off, 64);
        m3 |= __shfl_down(m3, off, 64);
    }
    if ((threadIdx.x & 63) == 0) {
        if (m0) atomicOr(&sm[0], m0);
        if (m1) atomicOr(&sm[1], m1);
        if (m2) atomicOr(&sm[2], m2);
        if (m3) atomicOr(&sm[3], m3);
    }
    __syncthreads();
    if (threadIdx.x < 4) {
        unsigned v = sm[threadIdx.x];
        if (v) atomicOr(&mask[threadIdx.x], v);
    }
}

// ---------------------------------------------------------------------------
// Pass 2: one thread per float4 (4 consecutive k of one row)
__global__ void __launch_bounds__(256) map_kernel(
    const int* __restrict__ C,
    const float4* __restrict__ U4,
    const float2* __restrict__ uphi,
    const unsigned* __restrict__ mask,
    float4* __restrict__ out4,
    int total4)
{
    int idx = blockIdx.x * blockDim.x + threadIdx.x;
    if (idx >= total4) return;
    int row = idx >> 5;        // K/4 = 32 float4 per row
    int k0  = (idx & 31) << 2;

    float2 up = uphi[row];
    float u = up.x;
    float phi = up.y;

    // rank = popcount of presence bits strictly below c
    int c = C[row];
    unsigned w0 = mask[0], w1 = mask[1], w2 = mask[2], w3 = mask[3];
    int cw = c >> 5;
    unsigned below = (1u << (c & 31)) - 1u;
    int rank = __popc(w0 & ((0 < cw) ? 0xFFFFFFFFu : ((0 == cw) ? below : 0u)))
             + __popc(w1 & ((1 < cw) ? 0xFFFFFFFFu : ((1 == cw) ? below : 0u)))
             + __popc(w2 & ((2 < cw) ? 0xFFFFFFFFu : ((2 == cw) ? below : 0u)))
             + __popc(w3 & ((3 < cw) ? 0xFFFFFFFFu : ((3 == cw) ? below : 0u)));

    float4 Uv = U4[idx];
    const float lo = 1e-7f;
    const float hi = 0.99999988079071045f;  // fp32(1 - 1e-7), matches jnp.clip

    float p0 = fminf(fmaxf(Uv.x, lo), hi) * phi;
    float p1 = fminf(fmaxf(Uv.y, lo), hi) * phi;
    float p2 = fminf(fmaxf(Uv.z, lo), hi) * phi;
    float p3 = fminf(fmaxf(Uv.w, lo), hi) * phi;

    float z0 = ndtri_acklam(p0);
    float z1 = ndtri_acklam(p1);
    float z2 = ndtri_acklam(p2);
    float z3 = ndtri_acklam(p3);

    float4 o;
    o.x = (k0 + 0 == rank) ? u : z0;
    o.y = (k0 + 1 == rank) ? u : z1;
    o.z = (k0 + 2 == rank) ? u : z2;
    o.w = (k0 + 3 == rank) ? u : z3;
    out4[idx] = o;
}

extern "C" void kernel_launch(void* const* d_in, const int* in_sizes, int n_in,
                              void* d_out, int out_size, void* d_ws, size_t ws_size,
                              hipStream_t stream) {
    const int*   C     = (const int*)d_in[0];
    const float* eps   = (const float*)d_in[1];
    const float4* U4   = (const float4*)d_in[2];
    const float* mu    = (const float*)d_in[3];
    const float* sigma = (const float*)d_in[4];
    float4* out4 = (float4*)d_out;

    unsigned* mask = (unsigned*)d_ws;
    float2* uphi = (float2*)((char*)d_ws + 256);

    int n = in_sizes[0];           // B*N = 262144 rows
    int total4 = out_size / 4;     // 8388608 float4s

    // ws is re-poisoned to 0xAA before every timed launch — zero the bitmap.
    hipMemsetAsync(d_ws, 0, 4 * sizeof(unsigned), stream);

    int rb = (n + 255) / 256;
    row_kernel<<<rb, 256, 0, stream>>>(C, eps, mu, sigma, mask, uphi, n);

    int mb = (total4 + 255) / 256;
    map_kernel<<<mb, 256, 0, stream>>>(C, U4, uphi, mask, out4, total4);
}